// Round 7
// baseline (262.788 us; speedup 1.0000x reference)
//
#include <hip/hip_runtime.h>

#define KDIM 768
#define MANS 640      // L*B*T
#define VV   30000
#define NKS  (KDIM / 64)                   // 12 k-steps
#define NBLK 469                           // ceil(30000/64) n-panels
#define VELEM (VV * KDIM)                  // 23,040,000 floats in vocab
#define CVTBLK ((VELEM + 8191) / 8192)     // 2813 conversion blocks
#define A2BLK  ((MANS / 64) * (KDIM / 128))  // 60 gemm blocks

typedef __attribute__((ext_vector_type(4)))  float  f32x4;
typedef __attribute__((ext_vector_type(16))) float  f32x16;
typedef __attribute__((ext_vector_type(8)))  __bf16 bf16x8;
typedef __attribute__((ext_vector_type(8)))  unsigned short ushort8;

// native f32->bf16 (RNE via v_cvt_pk_bf16_f32; compiler packs pairs — m240)
__device__ __forceinline__ unsigned short f2bf(float f) {
    union { __bf16 h; unsigned short u; } t;
    t.h = (__bf16)f;
    return t.u;
}

__device__ __forceinline__ ushort8 cvt8(f32x4 a, f32x4 b) {
    union { bf16x8 h; ushort8 u; } c;
    c.h[0] = (__bf16)a.x; c.h[1] = (__bf16)a.y;
    c.h[2] = (__bf16)a.z; c.h[3] = (__bf16)a.w;
    c.h[4] = (__bf16)b.x; c.h[5] = (__bf16)b.y;
    c.h[6] = (__bf16)b.z; c.h[7] = (__bf16)b.w;
    return c.u;
}

__device__ __forceinline__ void load_lds16(const unsigned short* g, unsigned short* l) {
    __builtin_amdgcn_global_load_lds(
        (__attribute__((address_space(1))) void*)(void*)g,
        (__attribute__((address_space(3))) void*)l,
        16, 0, 0);
}

// A2F fragment layout (written by gemm_a2, read by gemm_big):
//   element (m, n):  mb=m>>7, wm=(m>>6)&1, fm=(m>>5)&1, colm=m&31
//                    kt=n>>6, g=(n>>4)&3, halfb=(n>>3)&1, e=n&7
//   off = ((((mb*12+kt)*2+wm)*2+fm)*4+g)*512 + (halfb*32+colm)*8 + e
//       = (16*(mb*12+kt) + 4*(2*wm+fm) + g)*512 + lane*8   [lane=halfb*32+colm]
__device__ __forceinline__ long a2f_off(int m, int n) {
    int mb = m >> 7, wm = (m >> 6) & 1, fm = (m >> 5) & 1, colm = m & 31;
    int kt = n >> 6, g = (n >> 4) & 3, halfb = (n >> 3) & 1, e = n & 7;
    return ((((long)(mb * 12 + kt) * 2 + wm) * 2 + fm) * 4 + g) * 512
         + (halfb * 32 + colm) * 8 + e;
}

// ===================== prep_small =====================
// blocks [0,144):   W[768][768] f32 -> Wt[k][d]=W[d][k] bf16 (64x64 tiles)
// blocks [144,304): c[m] = dot(answer[m], b)
__global__ __launch_bounds__(256) void prep_small(
    const float* __restrict__ W, const float* __restrict__ A,
    const float* __restrict__ b, unsigned short* __restrict__ Wt_bf,
    float* __restrict__ cvec)
{
    __shared__ float ts[64][65];
    const int blk = blockIdx.x;
    if (blk < 144) {
        int bx = (blk % 12) * 64, by = (blk / 12) * 64;
        int tx = threadIdx.x & 63, tg = threadIdx.x >> 6;
#pragma unroll
        for (int i = 0; i < 16; ++i) {
            int r = tg * 16 + i;
            ts[r][tx] = W[(long)(by + r) * KDIM + bx + tx];
        }
        __syncthreads();
#pragma unroll
        for (int i = 0; i < 16; ++i) {
            int r = tg * 16 + i;
            Wt_bf[(long)(bx + r) * KDIM + by + tx] = f2bf(ts[tx][r]);
        }
    } else {
        int row  = (blk - 144) * 4 + (threadIdx.x >> 6);
        int lane = threadIdx.x & 63;
        const float* ap = A + (long)row * KDIM;
        float s = 0.f;
#pragma unroll
        for (int i = 0; i < KDIM / 64; ++i) s += ap[i * 64 + lane] * b[i * 64 + lane];
#pragma unroll
        for (int off = 32; off; off >>= 1) s += __shfl_down(s, off, 64);
        if (lane == 0) cvec[row] = s;
    }
}

// ===================== a2 gemm + vocab cvt (fused grid) =====================
// blocks [0,60):      A2F[frag-order] = answer @ W  (bf16), single-buffer LDS.
// blocks [60,2873):   vocab f32 -> bf16 streaming cvt on the ~196 idle CUs.
__global__ __launch_bounds__(256) void gemm_a2(
    const float* __restrict__ Af, const unsigned short* __restrict__ Bp,
    unsigned short* __restrict__ outp,
    const float* __restrict__ vocab, unsigned short* __restrict__ vocab_bf)
{
    if (blockIdx.x >= A2BLK) {
        const long base = (long)(blockIdx.x - A2BLK) * 8192 + (long)threadIdx.x * 8;
#pragma unroll
        for (int p = 0; p < 4; ++p) {
            long idx = base + p * 2048;
            if (idx < VELEM) {
                f32x4 v0 = ((const f32x4*)(vocab + idx))[0];
                f32x4 v1 = ((const f32x4*)(vocab + idx))[1];
                *(ushort8*)(vocab_bf + idx) = cvt8(v0, v1);
            }
        }
        return;
    }

    constexpr int TM = 64, TN = 128;
    __shared__ unsigned short sA[TM * 64];   // 8 KB
    __shared__ unsigned short sB[TN * 64];   // 16 KB

    const int t    = threadIdx.x;
    const int lane = t & 63;
    const int w    = t >> 6;
    const int wm   = w >> 1;
    const int wn   = w & 1;
    const int half = lane >> 5;
    const int col  = lane & 31;
    const long m0  = (long)(blockIdx.x % (MANS / 64)) * TM;
    const long n0  = (long)(blockIdx.x / (MANS / 64)) * TN;

    f32x16 acc[2];
    acc[0] = (f32x16)(0.f);
    acc[1] = (f32x16)(0.f);

    // A reg-stage addressing: 512 16B chunks, 2 per thread
    const float* gaf[2]; int laOff[2];
#pragma unroll
    for (int j = 0; j < 2; ++j) {
        int s   = (j * 4 + w) * 64 + lane;
        int row = s >> 3;
        int c   = (s & 7) ^ (row & 7);
        gaf[j]   = Af + (m0 + row) * KDIM + c * 8;
        laOff[j] = s * 8;
    }
    // B DMA addressing: 1024 chunks, source XOR-swizzled, dest wave-uniform
    const unsigned short* gb[4]; unsigned short* lbB[4];
#pragma unroll
    for (int j = 0; j < 4; ++j) {
        int s   = (j * 4 + w) * 64 + lane;
        int row = s >> 3;
        int c   = (s & 7) ^ (row & 7);
        gb[j]  = Bp + (n0 + row) * KDIM + c * 8;
        lbB[j] = &sB[(j * 4 + w) * 64 * 8];
    }

    for (int k0 = 0; k0 < KDIM; k0 += 64) {
#pragma unroll
        for (int j = 0; j < 4; ++j) load_lds16(gb[j] + k0, lbB[j]);
#pragma unroll
        for (int j = 0; j < 2; ++j) {
            f32x4 v0 = ((const f32x4*)(gaf[j] + k0))[0];
            f32x4 v1 = ((const f32x4*)(gaf[j] + k0))[1];
            *(ushort8*)(&sA[0] + laOff[j]) = cvt8(v0, v1);
        }
        __syncthreads();

#pragma unroll
        for (int g = 0; g < 4; ++g) {
            const int cg = g * 2 + half;
            int arow = wm * 32 + col;
            bf16x8 af = *(const bf16x8*)&sA[(arow * 8 + (cg ^ (arow & 7))) * 8];
#pragma unroll
            for (int fn = 0; fn < 2; ++fn) {
                int brow = wn * 64 + fn * 32 + col;
                bf16x8 bfv = *(const bf16x8*)&sB[(brow * 8 + (cg ^ (brow & 7))) * 8];
                acc[fn] = __builtin_amdgcn_mfma_f32_32x32x16_bf16(
                    af, bfv, acc[fn], 0, 0, 0);
            }
        }
        __syncthreads();
    }

    // epilogue: scatter into A2F fragment layout
#pragma unroll
    for (int fn = 0; fn < 2; ++fn) {
        int n = (int)n0 + wn * 64 + fn * 32 + col;
#pragma unroll
        for (int rg = 0; rg < 16; ++rg) {
            int m = (int)m0 + wm * 32 + (rg & 3) + 8 * (rg >> 2) + 4 * half;
            outp[a2f_off(m, n)] = f2bf(acc[fn][rg]);
        }
    }
}

// ===================== big gemm: out = A2F @ vocab_bf^T + c =====================
// ONE block = one 64-wide n-panel x ALL 640 m. B panel (64x768 bf16 = 96 KB,
// STATIC LDS — dynamic-LDS >64KB launch was the suspected round-6 failure)
// DMA'd to LDS ONCE -> B fetched exactly once device-wide (46 MB, was ~230 MB
// effective with L2 thrash). A operands stream as fragments from L2-resident
// A2F. After the single __syncthreads there are ZERO barriers and ZERO staging
// in the hot loop — nothing for the in-order vmcnt queue to serialize (rounds
// 3/5 showed scheduling around per-kstep barriers is a dead end).
// 512 threads = 8 waves (2/SIMD, 1 block/CU at 96 KB LDS). Waves: wm=w>>1
// (m 4x32), wn=w&1 (n 2x32). Per (m_idx,kt): 4 A-frag loads + 4 LDS reads
// + 4 MFMA (2 indep acc chains).
__global__ __launch_bounds__(512) void gemm_big(
    const unsigned short* __restrict__ A, const unsigned short* __restrict__ Bbf,
    const float* __restrict__ cvec, float* __restrict__ outp)
{
    __shared__ unsigned short panel[NKS * 4096];   // 12 tiles x 4096 ushorts = 96 KB

    const int t    = threadIdx.x;
    const int lane = t & 63;
    const int w    = t >> 6;       // 0..7
    const int wm   = w >> 1;       // 0..3 : m-subchunk (32 rows) within 128-span
    const int wn   = w & 1;        // 0..1 : n-subchunk (32 cols)
    const int half = lane >> 5;
    const int col  = lane & 31;
    const long n0  = (long)blockIdx.x * 64;

    // ---- stage full B panel via DMA, once: 12 tiles, 1 chunk/thread/tile ----
    {
        int row   = t >> 3;                       // 0..63
        int c     = (t & 7) ^ (row & 7);          // source XOR pre-swizzle
        long grow = n0 + row; if (grow > VV - 1) grow = VV - 1;
        const unsigned short* src = Bbf + grow * KDIM + c * 8;
        unsigned short*       dst = panel + w * 512;   // wave-uniform base
#pragma unroll
        for (int kt = 0; kt < NKS; ++kt)
            load_lds16(src + kt * 64, dst + kt * 4096);
    }
    __syncthreads();   // vmcnt(0)+barrier — the ONLY sync in this kernel

    // per-thread constants
    const int brow = wn * 32 + col;
    int boff[4];
#pragma unroll
    for (int g = 0; g < 4; ++g)
        boff[g] = (brow * 8 + (((g * 2 + half)) ^ (brow & 7))) * 8;

    const long nstore = n0 + wn * 32 + col;
    const bool nok    = (nstore < VV);

#pragma unroll 1
    for (int m_idx = 0; m_idx < 5; ++m_idx) {
        f32x16 acc0 = (f32x16)(0.f), acc1 = (f32x16)(0.f);
        // A2F base for this (m_idx, wm): off = (16*(m_idx*12+kt)+4*wm+g)*512+lane*8
        const unsigned short* aM = A + ((long)(16 * (m_idx * 12) + 4 * wm)) * 512
                                     + lane * 8;
#pragma unroll
        for (int kt = 0; kt < NKS; ++kt) {
            const unsigned short* aK = aM + (long)kt * (16 * 512);
            const unsigned short* pk = panel + kt * 4096;
            bf16x8 af0 = *(const bf16x8*)(aK + 0 * 512);
            bf16x8 af1 = *(const bf16x8*)(aK + 1 * 512);
            bf16x8 af2 = *(const bf16x8*)(aK + 2 * 512);
            bf16x8 af3 = *(const bf16x8*)(aK + 3 * 512);
            bf16x8 b0  = *(const bf16x8*)(pk + boff[0]);
            bf16x8 b1  = *(const bf16x8*)(pk + boff[1]);
            bf16x8 b2  = *(const bf16x8*)(pk + boff[2]);
            bf16x8 b3  = *(const bf16x8*)(pk + boff[3]);
            acc0 = __builtin_amdgcn_mfma_f32_32x32x16_bf16(af0, b0, acc0, 0, 0, 0);
            acc1 = __builtin_amdgcn_mfma_f32_32x32x16_bf16(af1, b1, acc1, 0, 0, 0);
            acc0 = __builtin_amdgcn_mfma_f32_32x32x16_bf16(af2, b2, acc0, 0, 0, 0);
            acc1 = __builtin_amdgcn_mfma_f32_32x32x16_bf16(af3, b3, acc1, 0, 0, 0);
        }
        if (nok) {
            f32x16 fa = acc0 + acc1;
            const long mbase = (long)m_idx * 128 + wm * 32 + 4 * half;
#pragma unroll
            for (int rg = 0; rg < 16; ++rg) {
                long m = mbase + (rg & 3) + 8 * (rg >> 2);
                outp[m * (long)VV + nstore] = fa[rg] + cvec[m];
            }
        }
    }
}

extern "C" void kernel_launch(void* const* d_in, const int* in_sizes, int n_in,
                              void* d_out, int out_size, void* d_ws, size_t ws_size,
                              hipStream_t stream) {
    const float* answer = (const float*)d_in[0];   // [640][768] f32
    const float* vocab  = (const float*)d_in[1];   // [30000][768] f32
    const float* W      = (const float*)d_in[2];   // [768][768] f32
    const float* bvec   = (const float*)d_in[3];   // [768] f32

    char* ws = (char*)d_ws;
    unsigned short* Wt_bf   = (unsigned short*)ws;                      // 1,179,648 B
    unsigned short* A2F     = (unsigned short*)(ws + 1179648);          //   983,040 B
    float*          cptr    = (float*)(ws + 1179648 + 983040);          //     2,560 B
    unsigned short* vocabbf = (unsigned short*)(ws + 2165248);          // 46,080,000 B

    // 1. Wt = W^T (bf16), c = answer @ b
    prep_small<<<304, 256, 0, stream>>>(W, answer, bvec, Wt_bf, cptr);

    // 2. A2F = answer @ W in fragment order (60 blocks) ∥ vocab f32->bf16 (2813)
    gemm_a2<<<A2BLK + CVTBLK, 256, 0, stream>>>(answer, Wt_bf, A2F, vocab, vocabbf);

    // 3. out[m][v] = sum_k A2F[m][k] * vocab_bf(v,k) + c[m]
    //    469 n-panel blocks, 512 threads, 96 KB STATIC LDS, barrier-free K-loop.
    gemm_big<<<NBLK, 512, 0, stream>>>(A2F, vocabbf, cptr, (float*)d_out);
}

// Round 8
// 244.557 us; speedup vs baseline: 1.0745x; 1.0745x over previous
//
#include <hip/hip_runtime.h>

#define KDIM 768
#define MANS 640      // L*B*T
#define VV   30000
#define NGRP 235      // ceil(30000/128)
#define NKS  (KDIM / 64)                   // 12 k-steps
#define VELEM (VV * KDIM)                  // 23,040,000 floats in vocab
#define CVTBLK (VELEM / 8 / 256)           // 11250 conversion blocks (exact)
#define A2BLK  ((MANS / 64) * (KDIM / 128))  // 60 gemm blocks

typedef __attribute__((ext_vector_type(4)))  float  f32x4;
typedef __attribute__((ext_vector_type(16))) float  f32x16;
typedef __attribute__((ext_vector_type(8)))  __bf16 bf16x8;
typedef __attribute__((ext_vector_type(8)))  unsigned short ushort8;

// native f32->bf16 (RNE via v_cvt_pk_bf16_f32; compiler packs pairs — m240)
__device__ __forceinline__ unsigned short f2bf(float f) {
    union { __bf16 h; unsigned short u; } t;
    t.h = (__bf16)f;
    return t.u;
}

__device__ __forceinline__ ushort8 cvt8(f32x4 a, f32x4 b) {
    union { bf16x8 h; ushort8 u; } c;
    c.h[0] = (__bf16)a.x; c.h[1] = (__bf16)a.y;
    c.h[2] = (__bf16)a.z; c.h[3] = (__bf16)a.w;
    c.h[4] = (__bf16)b.x; c.h[5] = (__bf16)b.y;
    c.h[6] = (__bf16)b.z; c.h[7] = (__bf16)b.w;
    return c.u;
}

__device__ __forceinline__ void load_lds16(const unsigned short* g, unsigned short* l) {
    __builtin_amdgcn_global_load_lds(
        (__attribute__((address_space(1))) void*)(void*)g,
        (__attribute__((address_space(3))) void*)l,
        16, 0, 0);
}

// A2F fragment layout (written by gemm_a2, read by gemm_big):
//   element (m, n):  mb=m>>7, wm=(m>>6)&1, fm=(m>>5)&1, colm=m&31
//                    kt=n>>6, g=(n>>4)&3, halfb=(n>>3)&1, e=n&7
//   off = (16*(mb*12+kt) + 4*(2*wm+fm) + g)*512 + (halfb*32+colm)*8 + e
// Wave read: base + lane*8 -> coalesced 1 KB per fragment.
__device__ __forceinline__ long a2f_off(int m, int n) {
    int mb = m >> 7, wm = (m >> 6) & 1, fm = (m >> 5) & 1, colm = m & 31;
    int kt = n >> 6, g = (n >> 4) & 3, halfb = (n >> 3) & 1, e = n & 7;
    return ((((long)(mb * 12 + kt) * 2 + wm) * 2 + fm) * 4 + g) * 512
         + (halfb * 32 + colm) * 8 + e;
}

// VF fragment layout (vocab bf16, written by cvt, read by gemm_big):
//   element (v, k): nt=v>>5, colv=v&31, kt=k>>6, g=(k>>4)&3, hb=(k>>3)&1, e=k&7
//   off = (((nt*12 + kt)*4 + g)*64 + hb*32 + colv)*8 + e
// Wave read: base + lane*8 -> lane l gets vocab[nt*32 + (l&31)][kt*64+(2g+(l>>5))*8..]
// i.e. exactly the mfma_32x32x16 B-fragment. fn stride 24576, kt stride 2048, g 512.

// ===================== prep_small =====================
// blocks [0,144):   W[768][768] f32 -> Wt[k][d]=W[d][k] bf16 (64x64 tiles)
// blocks [144,304): c[m] = dot(answer[m], b)
__global__ __launch_bounds__(256) void prep_small(
    const float* __restrict__ W, const float* __restrict__ A,
    const float* __restrict__ b, unsigned short* __restrict__ Wt_bf,
    float* __restrict__ cvec)
{
    __shared__ float ts[64][65];
    const int blk = blockIdx.x;
    if (blk < 144) {
        int bx = (blk % 12) * 64, by = (blk / 12) * 64;
        int tx = threadIdx.x & 63, tg = threadIdx.x >> 6;
#pragma unroll
        for (int i = 0; i < 16; ++i) {
            int r = tg * 16 + i;
            ts[r][tx] = W[(long)(by + r) * KDIM + bx + tx];
        }
        __syncthreads();
#pragma unroll
        for (int i = 0; i < 16; ++i) {
            int r = tg * 16 + i;
            Wt_bf[(long)(bx + r) * KDIM + by + tx] = f2bf(ts[tx][r]);
        }
    } else {
        int row  = (blk - 144) * 4 + (threadIdx.x >> 6);
        int lane = threadIdx.x & 63;
        const float* ap = A + (long)row * KDIM;
        float s = 0.f;
#pragma unroll
        for (int i = 0; i < KDIM / 64; ++i) s += ap[i * 64 + lane] * b[i * 64 + lane];
#pragma unroll
        for (int off = 32; off; off >>= 1) s += __shfl_down(s, off, 64);
        if (lane == 0) cvec[row] = s;
    }
}

// ===================== a2 gemm + vocab->VF cvt (fused grid) =====================
// blocks [0,60):        A2F[frag-order] = answer @ W (bf16), single-buffer LDS.
// blocks [60,60+11250): vocab f32 -> bf16 in VF FRAGMENT order. Reads fully
//                       coalesced; writes scattered 16B (stores don't stall).
__global__ __launch_bounds__(256) void gemm_a2(
    const float* __restrict__ Af, const unsigned short* __restrict__ Bp,
    unsigned short* __restrict__ outp,
    const float* __restrict__ vocab, unsigned short* __restrict__ vocab_vf)
{
    if (blockIdx.x >= A2BLK) {
        // chunk id: one 8-elem k-chunk of one vocab row; 96 chunks/row.
        long id = (long)(blockIdx.x - A2BLK) * 256 + threadIdx.x;  // < 2,880,000
        int  v  = (int)(id / 96);
        int  kc = (int)(id % 96);
        const float* src = vocab + (long)v * KDIM + kc * 8;
        f32x4 v0 = ((const f32x4*)src)[0], v1 = ((const f32x4*)src)[1];
        int nt = v >> 5, colv = v & 31;
        int kt = kc >> 3, g = (kc >> 1) & 3, hb = kc & 1;
        long off = ((((long)nt * 12 + kt) * 4 + g) * 64 + hb * 32 + colv) * 8;
        *(ushort8*)(vocab_vf + off) = cvt8(v0, v1);
        return;
    }

    constexpr int TM = 64, TN = 128;
    __shared__ unsigned short sA[TM * 64];   // 8 KB
    __shared__ unsigned short sB[TN * 64];   // 16 KB

    const int t    = threadIdx.x;
    const int lane = t & 63;
    const int w    = t >> 6;
    const int wm   = w >> 1;
    const int wn   = w & 1;
    const int half = lane >> 5;
    const int col  = lane & 31;
    const long m0  = (long)(blockIdx.x % (MANS / 64)) * TM;
    const long n0  = (long)(blockIdx.x / (MANS / 64)) * TN;

    f32x16 acc[2];
    acc[0] = (f32x16)(0.f);
    acc[1] = (f32x16)(0.f);

    // A reg-stage addressing: 512 16B chunks, 2 per thread
    const float* gaf[2]; int laOff[2];
#pragma unroll
    for (int j = 0; j < 2; ++j) {
        int s   = (j * 4 + w) * 64 + lane;
        int row = s >> 3;
        int c   = (s & 7) ^ (row & 7);
        gaf[j]   = Af + (m0 + row) * KDIM + c * 8;
        laOff[j] = s * 8;
    }
    // B DMA addressing: 1024 chunks, source XOR-swizzled, dest wave-uniform
    const unsigned short* gb[4]; unsigned short* lbB[4];
#pragma unroll
    for (int j = 0; j < 4; ++j) {
        int s   = (j * 4 + w) * 64 + lane;
        int row = s >> 3;
        int c   = (s & 7) ^ (row & 7);
        gb[j]  = Bp + (n0 + row) * KDIM + c * 8;
        lbB[j] = &sB[(j * 4 + w) * 64 * 8];
    }

    for (int k0 = 0; k0 < KDIM; k0 += 64) {
#pragma unroll
        for (int j = 0; j < 4; ++j) load_lds16(gb[j] + k0, lbB[j]);
#pragma unroll
        for (int j = 0; j < 2; ++j) {
            f32x4 v0 = ((const f32x4*)(gaf[j] + k0))[0];
            f32x4 v1 = ((const f32x4*)(gaf[j] + k0))[1];
            *(ushort8*)(&sA[0] + laOff[j]) = cvt8(v0, v1);
        }
        __syncthreads();

#pragma unroll
        for (int g = 0; g < 4; ++g) {
            const int cg = g * 2 + half;
            int arow = wm * 32 + col;
            bf16x8 af = *(const bf16x8*)&sA[(arow * 8 + (cg ^ (arow & 7))) * 8];
#pragma unroll
            for (int fn = 0; fn < 2; ++fn) {
                int brow = wn * 64 + fn * 32 + col;
                bf16x8 bfv = *(const bf16x8*)&sB[(brow * 8 + (cg ^ (brow & 7))) * 8];
                acc[fn] = __builtin_amdgcn_mfma_f32_32x32x16_bf16(
                    af, bfv, acc[fn], 0, 0, 0);
            }
        }
        __syncthreads();
    }

    // epilogue: scatter into A2F fragment layout
#pragma unroll
    for (int fn = 0; fn < 2; ++fn) {
        int n = (int)n0 + wn * 64 + fn * 32 + col;
#pragma unroll
        for (int rg = 0; rg < 16; ++rg) {
            int m = (int)m0 + wm * 32 + (rg & 3) + 8 * (rg >> 2) + 4 * half;
            outp[a2f_off(m, n)] = f2bf(acc[fn][rg]);
        }
    }
}

// ===================== big gemm: out = A2F @ VF^T + c =====================
// LDS-FREE pure dataflow. Both operands pre-laid-out in fragment order; every
// operand load is a wave-coalesced 1 KB global load from L2/L3. No LDS, no
// DMA, no barriers, no drains -> nothing to serialize (rounds 1/3/5: barrier
// schedules null; round 7: TLP is the lever). Residency is VGPR-limited
// (~3 waves/SIMD, ~3 blocks/CU) instead of LDS-capped. 48 unrolled groups of
// {4 loads + 4 independent-chain MFMAs}; compiler pipelines with counted vmcnt.
// XCD-grouping kept: 5 m-blocks of one n-group share an XCD -> VF L2 reuse.
// Tail n-tiles 938/939 read workspace garbage; it only enters output lanes
// with n>=30000, which the store guard drops (per-j confinement of MFMA).
__global__ __launch_bounds__(256) void gemm_big(
    const unsigned short* __restrict__ A, const unsigned short* __restrict__ VF,
    const float* __restrict__ cvec, float* __restrict__ outp)
{
    const int id    = blockIdx.x;
    const int x     = id & 7;
    const int q     = id >> 3;
    const int m_idx = q % 5;
    const int n_grp = (q / 5) * 8 + x;
    if (n_grp >= NGRP) return;               // 25 pad blocks idle

    const int t    = threadIdx.x;
    const int lane = t & 63;
    const int w    = t >> 6;
    const int wm   = w >> 1;
    const int wn   = w & 1;
    const int half = lane >> 5;
    const int col  = lane & 31;
    const long n0  = (long)n_grp * 128;

    f32x16 acc[2][2];
#pragma unroll
    for (int i = 0; i < 2; ++i)
#pragma unroll
        for (int j = 0; j < 2; ++j) acc[i][j] = (f32x16)(0.f);

    // A: off = (16*(m_idx*12+kt) + 4*(2*wm+fm) + g)*512 + lane*8
    //    kt stride 8192, fm stride 2048, g stride 512 (ushorts)
    const unsigned short* aB = A + ((long)16 * (m_idx * 12) + 8 * wm) * 512
                                 + lane * 8;
    // B: off = (((nt32*12+kt)*4+g)*64 + lane)*8, nt32 = n_grp*4 + wn*2 + fn
    //    fn stride 24576, kt stride 2048, g stride 512 (ushorts)
    const unsigned short* bB = VF + (long)(n_grp * 4 + wn * 2) * 24576
                                  + lane * 8;

#pragma unroll
    for (int kt = 0; kt < NKS; ++kt) {
        const unsigned short* aK = aB + (long)kt * 8192;
        const unsigned short* bK = bB + (long)kt * 2048;
#pragma unroll
        for (int g = 0; g < 4; ++g) {
            bf16x8 af0 = *(const bf16x8*)(aK + g * 512);            // fm=0
            bf16x8 af1 = *(const bf16x8*)(aK + 2048 + g * 512);     // fm=1
            bf16x8 bf0 = *(const bf16x8*)(bK + g * 512);            // fn=0
            bf16x8 bf1 = *(const bf16x8*)(bK + 24576 + g * 512);    // fn=1
            acc[0][0] = __builtin_amdgcn_mfma_f32_32x32x16_bf16(af0, bf0, acc[0][0], 0, 0, 0);
            acc[0][1] = __builtin_amdgcn_mfma_f32_32x32x16_bf16(af0, bf1, acc[0][1], 0, 0, 0);
            acc[1][0] = __builtin_amdgcn_mfma_f32_32x32x16_bf16(af1, bf0, acc[1][0], 0, 0, 0);
            acc[1][1] = __builtin_amdgcn_mfma_f32_32x32x16_bf16(af1, bf1, acc[1][1], 0, 0, 0);
        }
    }

    const long m0 = (long)m_idx * 128;
#pragma unroll
    for (int fm = 0; fm < 2; ++fm)
#pragma unroll
        for (int fn = 0; fn < 2; ++fn) {
            long n = n0 + wn * 64 + fn * 32 + col;
            if (n < VV) {
#pragma unroll
                for (int rg = 0; rg < 16; ++rg) {
                    long m = m0 + wm * 64 + fm * 32
                           + (rg & 3) + 8 * (rg >> 2) + 4 * half;
                    outp[m * (long)VV + n] = acc[fm][fn][rg] + cvec[m];
                }
            }
        }
}

extern "C" void kernel_launch(void* const* d_in, const int* in_sizes, int n_in,
                              void* d_out, int out_size, void* d_ws, size_t ws_size,
                              hipStream_t stream) {
    const float* answer = (const float*)d_in[0];   // [640][768] f32
    const float* vocab  = (const float*)d_in[1];   // [30000][768] f32
    const float* W      = (const float*)d_in[2];   // [768][768] f32
    const float* bvec   = (const float*)d_in[3];   // [768] f32

    char* ws = (char*)d_ws;
    unsigned short* Wt_bf   = (unsigned short*)ws;                      // 1,179,648 B
    unsigned short* A2F     = (unsigned short*)(ws + 1179648);          //   983,040 B
    float*          cptr    = (float*)(ws + 1179648 + 983040);          //     2,560 B
    unsigned short* VF      = (unsigned short*)(ws + 2165248);          // ~46.1 MB

    // 1. Wt = W^T (bf16), c = answer @ b
    prep_small<<<304, 256, 0, stream>>>(W, answer, bvec, Wt_bf, cptr);

    // 2. A2F = answer @ W in fragment order (60 blocks) ∥ vocab -> VF (11250)
    gemm_a2<<<A2BLK + CVTBLK, 256, 0, stream>>>(answer, Wt_bf, A2F, vocab, VF);

    // 3. out[m][v] = sum_k A2F[m][k] * VF(v,k) + c[m]
    //    1200 blocks (25 idle), XCD-grouped, LDS-free pure-dataflow GEMM.
    gemm_big<<<1200, 256, 0, stream>>>(A2F, VF, cptr, (float*)d_out);
}

// Round 9
// 220.476 us; speedup vs baseline: 1.1919x; 1.1092x over previous
//
#include <hip/hip_runtime.h>

#define KDIM 768
#define MANS 640      // L*B*T
#define VV   30000
#define NGRP 235      // ceil(30000/128)
#define NKS  (KDIM / 64)                   // 12 k-steps
#define NT   938                           // ceil(30000/32) vocab row-tiles
#define CVTBLK (NT * NKS)                  // 11256 cvt blocks: one (nt,kt) each
#define A2BLK  ((MANS / 64) * (KDIM / 128))  // 60 gemm blocks

typedef __attribute__((ext_vector_type(4)))  float  f32x4;
typedef __attribute__((ext_vector_type(16))) float  f32x16;
typedef __attribute__((ext_vector_type(8)))  __bf16 bf16x8;
typedef __attribute__((ext_vector_type(8)))  unsigned short ushort8;

// native f32->bf16 (RNE via v_cvt_pk_bf16_f32; compiler packs pairs — m240)
__device__ __forceinline__ unsigned short f2bf(float f) {
    union { __bf16 h; unsigned short u; } t;
    t.h = (__bf16)f;
    return t.u;
}

__device__ __forceinline__ ushort8 cvt8(f32x4 a, f32x4 b) {
    union { bf16x8 h; ushort8 u; } c;
    c.h[0] = (__bf16)a.x; c.h[1] = (__bf16)a.y;
    c.h[2] = (__bf16)a.z; c.h[3] = (__bf16)a.w;
    c.h[4] = (__bf16)b.x; c.h[5] = (__bf16)b.y;
    c.h[6] = (__bf16)b.z; c.h[7] = (__bf16)b.w;
    return c.u;
}

__device__ __forceinline__ void load_lds16(const unsigned short* g, unsigned short* l) {
    __builtin_amdgcn_global_load_lds(
        (__attribute__((address_space(1))) void*)(void*)g,
        (__attribute__((address_space(3))) void*)l,
        16, 0, 0);
}

// A2F fragment layout (written by gemm_a2, read by gemm_big):
//   off = (16*(mb*12+kt) + 4*(2*wm+fm) + g)*512 + lane*8  [lane=(halfb,colm)]
__device__ __forceinline__ long a2f_off(int m, int n) {
    int mb = m >> 7, wm = (m >> 6) & 1, fm = (m >> 5) & 1, colm = m & 31;
    int kt = n >> 6, g = (n >> 4) & 3, halfb = (n >> 3) & 1, e = n & 7;
    return ((((long)(mb * 12 + kt) * 2 + wm) * 2 + fm) * 4 + g) * 512
         + (halfb * 32 + colm) * 8 + e;
}

// VF fragment layout: element (v,k): nt=v>>5, colv=v&31, kt=k>>6, g=(k>>4)&3,
// hb=(k>>3)&1, e=k&7; off = (((nt*12+kt)*4+g)*64 + hb*32 + colv)*8 + e.
// Wave read at base+lane*8 = exact mfma_32x32x16 B-fragment.
// nt stride 24576, kt stride 2048, g stride 512 (ushorts).

// ===================== prep_small =====================
__global__ __launch_bounds__(256) void prep_small(
    const float* __restrict__ W, const float* __restrict__ A,
    const float* __restrict__ b, unsigned short* __restrict__ Wt_bf,
    float* __restrict__ cvec)
{
    __shared__ float ts[64][65];
    const int blk = blockIdx.x;
    if (blk < 144) {
        int bx = (blk % 12) * 64, by = (blk / 12) * 64;
        int tx = threadIdx.x & 63, tg = threadIdx.x >> 6;
#pragma unroll
        for (int i = 0; i < 16; ++i) {
            int r = tg * 16 + i;
            ts[r][tx] = W[(long)(by + r) * KDIM + bx + tx];
        }
        __syncthreads();
#pragma unroll
        for (int i = 0; i < 16; ++i) {
            int r = tg * 16 + i;
            Wt_bf[(long)(bx + r) * KDIM + by + tx] = f2bf(ts[tx][r]);
        }
    } else {
        int row  = (blk - 144) * 4 + (threadIdx.x >> 6);
        int lane = threadIdx.x & 63;
        const float* ap = A + (long)row * KDIM;
        float s = 0.f;
#pragma unroll
        for (int i = 0; i < KDIM / 64; ++i) s += ap[i * 64 + lane] * b[i * 64 + lane];
#pragma unroll
        for (int off = 32; off; off >>= 1) s += __shfl_down(s, off, 64);
        if (lane == 0) cvec[row] = s;
    }
}

// ===================== a2 gemm + vocab->VF cvt (fused grid) =====================
// blocks [0,60):            A2F = answer @ W (bf16), single-buffer LDS.
// blocks [60,60+11256):     one block = one (nt,kt): vocab f32 -> VF bf16.
//   Thread t: colv=t&31, hb=(t>>5)&1, g=t>>6. Reads 32B/lane (pair-merged to
//   64B segments); WRITES PERFECTLY LINEAR: VF[(bid*4+g)*512 + hb*256 + colv*8]
//   -> each wave stores 1 KB contiguous (R8's 16B-scatter writes cost ~10us).
__global__ __launch_bounds__(256) void gemm_a2(
    const float* __restrict__ Af, const unsigned short* __restrict__ Bp,
    unsigned short* __restrict__ outp,
    const float* __restrict__ vocab, unsigned short* __restrict__ vocab_vf)
{
    if (blockIdx.x >= A2BLK) {
        const int bid  = blockIdx.x - A2BLK;       // 0..11255 = nt*12 + kt
        const int nt   = bid / NKS;
        const int kt   = bid % NKS;
        const int t    = threadIdx.x;
        const int colv = t & 31;
        const int hb   = (t >> 5) & 1;
        const int g    = t >> 6;
        long row = (long)nt * 32 + colv;
        if (row > VV - 1) row = VV - 1;            // clamp tail rows (nt=937)
        const float* src = vocab + row * KDIM + kt * 64 + g * 16 + hb * 8;
        f32x4 v0 = ((const f32x4*)src)[0], v1 = ((const f32x4*)src)[1];
        long off = ((long)bid * 4 + g) * 512 + hb * 256 + colv * 8;
        *(ushort8*)(vocab_vf + off) = cvt8(v0, v1);
        return;
    }

    constexpr int TM = 64, TN = 128;
    __shared__ unsigned short sA[TM * 64];   // 8 KB
    __shared__ unsigned short sB[TN * 64];   // 16 KB

    const int t    = threadIdx.x;
    const int lane = t & 63;
    const int w    = t >> 6;
    const int wm   = w >> 1;
    const int wn   = w & 1;
    const int half = lane >> 5;
    const int col  = lane & 31;
    const long m0  = (long)(blockIdx.x % (MANS / 64)) * TM;
    const long n0  = (long)(blockIdx.x / (MANS / 64)) * TN;

    f32x16 acc[2];
    acc[0] = (f32x16)(0.f);
    acc[1] = (f32x16)(0.f);

    const float* gaf[2]; int laOff[2];
#pragma unroll
    for (int j = 0; j < 2; ++j) {
        int s   = (j * 4 + w) * 64 + lane;
        int row = s >> 3;
        int c   = (s & 7) ^ (row & 7);
        gaf[j]   = Af + (m0 + row) * KDIM + c * 8;
        laOff[j] = s * 8;
    }
    const unsigned short* gb[4]; unsigned short* lbB[4];
#pragma unroll
    for (int j = 0; j < 4; ++j) {
        int s   = (j * 4 + w) * 64 + lane;
        int row = s >> 3;
        int c   = (s & 7) ^ (row & 7);
        gb[j]  = Bp + (n0 + row) * KDIM + c * 8;
        lbB[j] = &sB[(j * 4 + w) * 64 * 8];
    }

    for (int k0 = 0; k0 < KDIM; k0 += 64) {
#pragma unroll
        for (int j = 0; j < 4; ++j) load_lds16(gb[j] + k0, lbB[j]);
#pragma unroll
        for (int j = 0; j < 2; ++j) {
            f32x4 v0 = ((const f32x4*)(gaf[j] + k0))[0];
            f32x4 v1 = ((const f32x4*)(gaf[j] + k0))[1];
            *(ushort8*)(&sA[0] + laOff[j]) = cvt8(v0, v1);
        }
        __syncthreads();

#pragma unroll
        for (int g = 0; g < 4; ++g) {
            const int cg = g * 2 + half;
            int arow = wm * 32 + col;
            bf16x8 af = *(const bf16x8*)&sA[(arow * 8 + (cg ^ (arow & 7))) * 8];
#pragma unroll
            for (int fn = 0; fn < 2; ++fn) {
                int brow = wn * 64 + fn * 32 + col;
                bf16x8 bfv = *(const bf16x8*)&sB[(brow * 8 + (cg ^ (brow & 7))) * 8];
                acc[fn] = __builtin_amdgcn_mfma_f32_32x32x16_bf16(
                    af, bfv, acc[fn], 0, 0, 0);
            }
        }
        __syncthreads();
    }

#pragma unroll
    for (int fn = 0; fn < 2; ++fn) {
        int n = (int)n0 + wn * 64 + fn * 32 + col;
#pragma unroll
        for (int rg = 0; rg < 16; ++rg) {
            int m = (int)m0 + wm * 32 + (rg & 3) + 8 * (rg >> 2) + 4 * half;
            outp[a2f_off(m, n)] = f2bf(acc[fn][rg]);
        }
    }
}

// ===================== big gemm: out = A2F @ VF^T + c =====================
// R8 pure-dataflow + EXPLICIT 1-kstep register double-buffer. R8 taught: the
// compiler register-minimizes (VGPR=64, ~4 loads in flight) -> ~700cy L3
// latency exposed per load group. Fix: name the prefetch regs. fa/fb[2][..][4]
// fully-unrolled kt loop -> static indices (rule #20). In-order vmem queue:
// kt's 16 frags are OLDER than kt+1's -> compiler's pre-MFMA wait is a counted
// vmcnt(16). 16 loads in flight/wave x 8 waves/CU; zero LDS, zero barriers.
// __launch_bounds__(256,2): ~205 live VGPRs (128 staged + 64 acc + addr).
__global__ __launch_bounds__(256, 2) void gemm_big(
    const unsigned short* __restrict__ A, const unsigned short* __restrict__ VF,
    const float* __restrict__ cvec, float* __restrict__ outp)
{
    const int id    = blockIdx.x;
    const int x     = id & 7;
    const int q     = id >> 3;
    const int m_idx = q % 5;
    const int n_grp = (q / 5) * 8 + x;
    if (n_grp >= NGRP) return;               // 25 pad blocks idle

    const int t    = threadIdx.x;
    const int lane = t & 63;
    const int w    = t >> 6;
    const int wm   = w >> 1;
    const int wn   = w & 1;
    const int half = lane >> 5;
    const int col  = lane & 31;
    const long n0  = (long)n_grp * 128;

    f32x16 acc[2][2];
#pragma unroll
    for (int i = 0; i < 2; ++i)
#pragma unroll
        for (int j = 0; j < 2; ++j) acc[i][j] = (f32x16)(0.f);

    // A: kt stride 8192, fm stride 2048, g stride 512 (ushorts)
    const unsigned short* aB = A + ((long)16 * (m_idx * 12) + 8 * wm) * 512
                                 + lane * 8;
    // B: per-fn base, nt32 clamped to 937 (tail n-tiles; stores guarded)
    int nt0 = n_grp * 4 + wn * 2;     if (nt0 > NT - 1) nt0 = NT - 1;
    int nt1 = n_grp * 4 + wn * 2 + 1; if (nt1 > NT - 1) nt1 = NT - 1;
    const unsigned short* bB0 = VF + (long)nt0 * 24576 + lane * 8;
    const unsigned short* bB1 = VF + (long)nt1 * 24576 + lane * 8;

    bf16x8 fa[2][2][4];   // [buf][fm][g]
    bf16x8 fb[2][2][4];   // [buf][fn][g]

    // prologue: load kt=0 into buf 0
#pragma unroll
    for (int g = 0; g < 4; ++g) {
        fa[0][0][g] = *(const bf16x8*)(aB + g * 512);
        fa[0][1][g] = *(const bf16x8*)(aB + 2048 + g * 512);
        fb[0][0][g] = *(const bf16x8*)(bB0 + g * 512);
        fb[0][1][g] = *(const bf16x8*)(bB1 + g * 512);
    }

#pragma unroll
    for (int kt = 0; kt < NKS; ++kt) {
        const int cur = kt & 1, nxt = cur ^ 1;
        if (kt < NKS - 1) {                  // prefetch kt+1 (newest in queue)
            const unsigned short* aK = aB + (long)(kt + 1) * 8192;
            const unsigned short* bK0 = bB0 + (long)(kt + 1) * 2048;
            const unsigned short* bK1 = bB1 + (long)(kt + 1) * 2048;
#pragma unroll
            for (int g = 0; g < 4; ++g) {
                fa[nxt][0][g] = *(const bf16x8*)(aK + g * 512);
                fa[nxt][1][g] = *(const bf16x8*)(aK + 2048 + g * 512);
                fb[nxt][0][g] = *(const bf16x8*)(bK0 + g * 512);
                fb[nxt][1][g] = *(const bf16x8*)(bK1 + g * 512);
            }
        }
        // MFMAs on buf cur: counted vmcnt wait (16 newer outstanding)
#pragma unroll
        for (int g = 0; g < 4; ++g) {
            acc[0][0] = __builtin_amdgcn_mfma_f32_32x32x16_bf16(
                fa[cur][0][g], fb[cur][0][g], acc[0][0], 0, 0, 0);
            acc[0][1] = __builtin_amdgcn_mfma_f32_32x32x16_bf16(
                fa[cur][0][g], fb[cur][1][g], acc[0][1], 0, 0, 0);
            acc[1][0] = __builtin_amdgcn_mfma_f32_32x32x16_bf16(
                fa[cur][1][g], fb[cur][0][g], acc[1][0], 0, 0, 0);
            acc[1][1] = __builtin_amdgcn_mfma_f32_32x32x16_bf16(
                fa[cur][1][g], fb[cur][1][g], acc[1][1], 0, 0, 0);
        }
    }

    const long m0 = (long)m_idx * 128;
#pragma unroll
    for (int fm = 0; fm < 2; ++fm)
#pragma unroll
        for (int fn = 0; fn < 2; ++fn) {
            long n = n0 + wn * 64 + fn * 32 + col;
            if (n < VV) {
#pragma unroll
                for (int rg = 0; rg < 16; ++rg) {
                    long m = m0 + wm * 64 + fm * 32
                           + (rg & 3) + 8 * (rg >> 2) + 4 * half;
                    outp[m * (long)VV + n] = acc[fm][fn][rg] + cvec[m];
                }
            }
        }
}

extern "C" void kernel_launch(void* const* d_in, const int* in_sizes, int n_in,
                              void* d_out, int out_size, void* d_ws, size_t ws_size,
                              hipStream_t stream) {
    const float* answer = (const float*)d_in[0];   // [640][768] f32
    const float* vocab  = (const float*)d_in[1];   // [30000][768] f32
    const float* W      = (const float*)d_in[2];   // [768][768] f32
    const float* bvec   = (const float*)d_in[3];   // [768] f32

    char* ws = (char*)d_ws;
    unsigned short* Wt_bf   = (unsigned short*)ws;                      // 1,179,648 B
    unsigned short* A2F     = (unsigned short*)(ws + 1179648);          //   983,040 B
    float*          cptr    = (float*)(ws + 1179648 + 983040);          //     2,560 B
    unsigned short* VF      = (unsigned short*)(ws + 2165248);          // 46,104,576 B

    // 1. Wt = W^T (bf16), c = answer @ b
    prep_small<<<304, 256, 0, stream>>>(W, answer, bvec, Wt_bf, cptr);

    // 2. A2F = answer @ W in fragment order (60 blocks) ∥ vocab -> VF (11256)
    gemm_a2<<<A2BLK + CVTBLK, 256, 0, stream>>>(answer, Wt_bf, A2F, vocab, VF);

    // 3. out[m][v] = sum_k A2F[m][k] * VF(v,k) + c[m]
    //    1200 blocks (25 idle), XCD-grouped, dataflow + reg double-buffer.
    gemm_big<<<1200, 256, 0, stream>>>(A2F, VF, cptr, (float*)d_out);
}